// Round 1
// baseline (199.768 us; speedup 1.0000x reference)
//
#include <hip/hip_runtime.h>

#define PH 7
#define PW 7
#define SSCALE 0.0625f
#define SR 2
#define CC 256
#define HH 200
#define WW 200

__global__ __launch_bounds__(256) void roi_align_kernel(
    const float* __restrict__ features, const float* __restrict__ rois,
    float* __restrict__ out, int total)
{
    int idx = blockIdx.x * blockDim.x + threadIdx.x;
    if (idx >= total) return;

    int pw = idx % PW;
    int ph = (idx / PW) % PH;
    int c  = (idx / (PW * PH)) % CC;
    int n  = idx / (PW * PH * CC);

    const float* r = rois + (size_t)n * 5;
    int   b  = (int)r[0];
    float x1 = r[1] * SSCALE;
    float y1 = r[2] * SSCALE;
    float x2 = r[3] * SSCALE;
    float y2 = r[4] * SSCALE;

    float roi_w = fmaxf(x2 - x1, 1.0f);
    float roi_h = fmaxf(y2 - y1, 1.0f);
    float bin_w = roi_w * (1.0f / PW);
    float bin_h = roi_h * (1.0f / PH);

    const float* fbase = features + ((size_t)b * CC + c) * (HH * WW);

    float acc = 0.0f;
    #pragma unroll
    for (int iy = 0; iy < SR; ++iy) {
        float y  = y1 + ((float)ph + ((float)iy + 0.5f) * (1.0f / SR)) * bin_h;
        bool  vy = (y >= -1.0f) && (y <= (float)HH);
        float cy = fmaxf(y, 0.0f);
        int   yl = min((int)floorf(cy), HH - 1);
        int   yh = min(yl + 1, HH - 1);
        float fy = (yl >= HH - 1) ? 0.0f : (cy - (float)yl);
        float hy = 1.0f - fy;
        float ly = fy;
        #pragma unroll
        for (int ix = 0; ix < SR; ++ix) {
            float x  = x1 + ((float)pw + ((float)ix + 0.5f) * (1.0f / SR)) * bin_w;
            bool  vx = (x >= -1.0f) && (x <= (float)WW);
            float cx = fmaxf(x, 0.0f);
            int   xl = min((int)floorf(cx), WW - 1);
            int   xh = min(xl + 1, WW - 1);
            float fx = (xl >= WW - 1) ? 0.0f : (cx - (float)xl);
            float hx = 1.0f - fx;
            float lx = fx;

            float v00 = fbase[yl * WW + xl];
            float v01 = fbase[yl * WW + xh];
            float v10 = fbase[yh * WW + xl];
            float v11 = fbase[yh * WW + xh];

            float v = hy * (hx * v00 + lx * v01) + ly * (hx * v10 + lx * v11);
            if (vy && vx) acc += v;
        }
    }
    out[idx] = acc * (1.0f / (SR * SR));
}

extern "C" void kernel_launch(void* const* d_in, const int* in_sizes, int n_in,
                              void* d_out, int out_size, void* d_ws, size_t ws_size,
                              hipStream_t stream) {
    const float* features = (const float*)d_in[0];
    const float* rois     = (const float*)d_in[1];
    float*       out      = (float*)d_out;

    int N     = in_sizes[1] / 5;            // 512
    int total = N * CC * PH * PW;           // matches out_size

    int block = 256;
    int grid  = (total + block - 1) / block;
    roi_align_kernel<<<grid, block, 0, stream>>>(features, rois, out, total);
}